// Round 10
// baseline (394.114 us; speedup 1.0000x reference)
//
#include <hip/hip_runtime.h>
#include <cstdint>
#include <cstddef>

typedef _Float16 half8 __attribute__((ext_vector_type(8)));
typedef float floatx4 __attribute__((ext_vector_type(4)));

constexpr int N = 16384;
constexpr int H = 4096;
constexpr int E = 64;
constexpr int BM = 64;            // rows per block (W staged once per 64 rows)
constexpr int KS = 4;             // split-K factor
constexpr int KPB = H / KS;       // 1024 K per block
constexpr int BK = 64;            // K per stage
constexpr int NST = KPB / BK;     // 16 stages
constexpr float XSCALE = 2048.0f;                      // 2^11
constexpr float WSCALE = 4096.0f;                      // 2^12
constexpr float DESCALE = 1.0f / (2048.0f * 4096.0f);  // 2^-23

// LDS per block = 48 KB -> 3 blocks/CU (144 KB), 24 waves/CU.
//   x   : 2 x 16 KB [0, 32768)     buf s&1; 64 rows x 256 B; seg swz ^(row&7)
//   Whi : 8 KB      [32768, 40960) SINGLE-buffered (two-barrier step)
//   Wlo : 8 KB      [40960, 49152)
// Staged bytes: x 256 MB + W 256 MB = 512 MB (R9 was 768 MB at the measured
// ~24 GB/s/CU staging-path ceiling -> bytes are the binding resource).
constexpr int XB = 16384;
constexpr int WHIO = 32768;
constexpr int WLOO = 40960;

__device__ __forceinline__ void async16(const void* g, void* l) {
  __builtin_amdgcn_global_load_lds(
      (const __attribute__((address_space(1))) void*)g,
      (__attribute__((address_space(3))) void*)l,
      16, 0, 0);
}

// ---------------- W split prekernel: W (f32) -> Whi + Wlo (f16), scaled by 2^12
__global__ __launch_bounds__(256) void wsplit_kernel(const float* __restrict__ W,
                                                     _Float16* __restrict__ Whi,
                                                     _Float16* __restrict__ Wlo) {
  int i = blockIdx.x * 256 + threadIdx.x;
  if (i >= E * H) return;
  float w = W[i] * WSCALE;
  _Float16 hi = (_Float16)w;
  _Float16 lo = (_Float16)(w - (float)hi);
  Whi[i] = hi;
  Wlo[i] = lo;
}

// split 8 f32 x-values (scaled by 2^11) into f16 hi/lo fragments
__device__ __forceinline__ void cvt_split(const float4& a, const float4& b,
                                          half8& hi, half8& lo) {
  float f[8] = {a.x, a.y, a.z, a.w, b.x, b.y, b.z, b.w};
#pragma unroll
  for (int i = 0; i < 8; ++i) {
    float s = f[i] * XSCALE;
    _Float16 h = (_Float16)s;
    _Float16 l = (_Float16)(s - (float)h);
    hi[i] = h;
    lo[i] = l;
  }
}

// Split-K GEMM. Grid = (N/BM)*KS = 1024 blocks x 512 threads -> 3 blocks/CU
// (48 KB LDS), 24 waves/CU. Two-barrier counted-vmcnt step (R9-proven):
//   [vmcnt(2); s_barrier]      queue [xa(s),xb(s),Wh(s),Wl(s),xa(s+1),xb(s+1)]
//                              -> retires stage-s quad, keeps x(s+1) in flight
//   issue 10 ds_reads; cvt_split (x frag)
//   [lgkmcnt(0); s_barrier]    all waves' reads retired -> bufs overwritable
//   issue Wh,Wl(s+1) -> fixed W buf; SB(0); issue xa,xb(s+2) -> x buf s&1
//   12 MFMA
// vmcnt never 0 mid-loop (T4); issue order pinned (in-order vmcnt).
// Wave split: kh = wv>>2 (K-subhalf), rowtile rt = wv&3 (16 rows each);
// each wave covers ALL 4 expert tiles: 12 MFMAs + 10 ds_read_b128 per stage.
__global__ __launch_bounds__(512, 6) void gemm_kernel(
    const float* __restrict__ x,
    const _Float16* __restrict__ Whi,
    const _Float16* __restrict__ Wlo,
    float* __restrict__ part) {
  __shared__ __align__(16) char smem[49152];

  const int tid = threadIdx.x;
  const int wv = tid >> 6;
  const int lane = tid & 63;
  const int c = lane & 15;
  const int q = lane >> 4;
  const int rowtile = blockIdx.x >> 2;
  const int ks = blockIdx.x & 3;
  const int r0 = rowtile * BM;
  const int k0 = ks * KPB;

  // ---- staging addresses: 4 async16 per thread per stage ----
  // x (16 KB = 2 loads): load A rows 0-31, load B rows 32-63; t -> row (t>>4),
  // phys seg t&15, log = phys ^ (row&7) ((32+r)&7 == r&7 -> same seg both)
  const int xr = tid >> 4;
  const float* gxA = x + (size_t)(r0 + xr) * H + k0 + (((tid & 15) ^ (xr & 7)) * 4);
  const float* gxB = gxA + (size_t)32 * H;
  const int xdA = tid * 16;
  const int xdB = 8192 + tid * 16;
  // Whi/Wlo (8 KB each = 1 load each): t -> expert t>>3, phys seg t&7,
  // log = phys ^ (e&7)
  const int we = tid >> 3;
  const int wlog = (tid & 7) ^ (we & 7);
  const _Float16* gwh = Whi + (size_t)we * H + k0 + wlog * 8;
  const _Float16* gwl = Wlo + (size_t)we * H + k0 + wlog * 8;
  const int wd = tid * 16;

  // ---- fragment LDS byte offsets ----
  const int kh = wv >> 2;
  const int rb = (wv & 3) << 4;
  const int fr = rb + c;
  const int sA = 8 * kh + 2 * q;
  const int xo0 = fr * 256 + ((sA ^ (c & 7)) * 16);
  const int xo1 = fr * 256 + (((sA + 1) ^ (c & 7)) * 16);
  const int wseg = ((4 * kh + q) ^ (c & 7)) * 16;
  const int wo0 = (0 * 16 + c) * 128 + wseg;
  const int wo1 = (1 * 16 + c) * 128 + wseg;
  const int wo2 = (2 * 16 + c) * 128 + wseg;
  const int wo3 = (3 * 16 + c) * 128 + wseg;

  auto stageX = [&](int s) {
    const int kc = s * BK;
    char* b = smem + (s & 1) * XB;
    async16(gxA + kc, b + xdA);
    async16(gxB + kc, b + xdB);
  };
  auto stageW = [&](int s) {
    const int kc = s * BK;
    async16(gwh + kc, smem + WHIO + wd);
    async16(gwl + kc, smem + WLOO + wd);
  };

  floatx4 acc0 = {0.f, 0.f, 0.f, 0.f};
  floatx4 acc1 = acc0, acc2 = acc0, acc3 = acc0;

  auto step = [&](int s, bool last) {
    if (!last)
      asm volatile("s_waitcnt vmcnt(2)\n\ts_barrier" ::: "memory");
    else
      asm volatile("s_waitcnt vmcnt(0)\n\ts_barrier" ::: "memory");
    const char* xb = smem + (s & 1) * XB;
    float4 xa = *(const float4*)(xb + xo0);
    float4 xv = *(const float4*)(xb + xo1);
    half8 h0 = *(const half8*)(smem + WHIO + wo0);
    half8 h1 = *(const half8*)(smem + WHIO + wo1);
    half8 h2 = *(const half8*)(smem + WHIO + wo2);
    half8 h3 = *(const half8*)(smem + WHIO + wo3);
    half8 l0 = *(const half8*)(smem + WLOO + wo0);
    half8 l1 = *(const half8*)(smem + WLOO + wo1);
    half8 l2 = *(const half8*)(smem + WLOO + wo2);
    half8 l3 = *(const half8*)(smem + WLOO + wo3);
    half8 ahi, alo;
    cvt_split(xa, xv, ahi, alo);  // x frag consumed before the drain barrier
    asm volatile("s_waitcnt lgkmcnt(0)\n\ts_barrier" ::: "memory");
    if (s + 1 < NST) stageW(s + 1);     // W slots BEFORE x slots (in-order vmcnt)
    __builtin_amdgcn_sched_barrier(0);
    if (s + 2 < NST) stageX(s + 2);

    acc0 = __builtin_amdgcn_mfma_f32_16x16x32_f16(alo, h0, acc0, 0, 0, 0);
    acc1 = __builtin_amdgcn_mfma_f32_16x16x32_f16(alo, h1, acc1, 0, 0, 0);
    acc2 = __builtin_amdgcn_mfma_f32_16x16x32_f16(alo, h2, acc2, 0, 0, 0);
    acc3 = __builtin_amdgcn_mfma_f32_16x16x32_f16(alo, h3, acc3, 0, 0, 0);
    acc0 = __builtin_amdgcn_mfma_f32_16x16x32_f16(ahi, l0, acc0, 0, 0, 0);
    acc1 = __builtin_amdgcn_mfma_f32_16x16x32_f16(ahi, l1, acc1, 0, 0, 0);
    acc2 = __builtin_amdgcn_mfma_f32_16x16x32_f16(ahi, l2, acc2, 0, 0, 0);
    acc3 = __builtin_amdgcn_mfma_f32_16x16x32_f16(ahi, l3, acc3, 0, 0, 0);
    acc0 = __builtin_amdgcn_mfma_f32_16x16x32_f16(ahi, h0, acc0, 0, 0, 0);
    acc1 = __builtin_amdgcn_mfma_f32_16x16x32_f16(ahi, h1, acc1, 0, 0, 0);
    acc2 = __builtin_amdgcn_mfma_f32_16x16x32_f16(ahi, h2, acc2, 0, 0, 0);
    acc3 = __builtin_amdgcn_mfma_f32_16x16x32_f16(ahi, h3, acc3, 0, 0, 0);
  };

  // ---- prologue: queue = [xa0,xb0,Wh0,Wl0 | xa1,xb1]; group order pinned ----
  stageX(0);
  __builtin_amdgcn_sched_barrier(0);
  stageW(0);
  __builtin_amdgcn_sched_barrier(0);
  stageX(1);

  for (int s = 0; s < NST - 1; ++s) step(s, false);
  step(NST - 1, true);

  // ---- reduce the 2 K-subhalves in LDS, write block partial ----
  __syncthreads();            // all waves done reading x bufs (red aliases them)
  float* red = (float*)smem;  // [2][64][64] = 32 KB
#pragma unroll
  for (int r = 0; r < 4; ++r) {
    const int row = rb + q * 4 + r;
    float* rp = red + (kh * 64 + row) * 64;
    rp[0 * 16 + c] = acc0[r];
    rp[1 * 16 + c] = acc1[r];
    rp[2 * 16 + c] = acc2[r];
    rp[3 * 16 + c] = acc3[r];
  }
  __syncthreads();

  // 8 waves x 8 rows; lane = expert
  const int rbase = wv * 8;
#pragma unroll
  for (int rr = rbase; rr < rbase + 8; ++rr) {
    float v = red[rr * 64 + lane] + red[(64 + rr) * 64 + lane];
    part[((size_t)ks * N + r0 + rr) * 64 + lane] = v;
  }
}

// Finalize: reduce split-K partials, softmax, top-2. Grid 4096 x 256 (wave/row).
__global__ __launch_bounds__(256) void finalize_kernel(
    const float* __restrict__ part,
    float* __restrict__ out_scores,
    float* __restrict__ out_w,
    float* __restrict__ out_i) {
  const int wv = threadIdx.x >> 6;
  const int lane = threadIdx.x & 63;
  const int row = blockIdx.x * 4 + wv;

  float v = (part[(size_t)row * 64 + lane] +
             part[((size_t)N + row) * 64 + lane]) +
            (part[((size_t)2 * N + row) * 64 + lane] +
             part[((size_t)3 * N + row) * 64 + lane]);
  v *= DESCALE;
  // softmax
  float m = v;
#pragma unroll
  for (int o = 32; o > 0; o >>= 1) m = fmaxf(m, __shfl_xor(m, o));
  float ev = __expf(v - m);
  float ssum = ev;
#pragma unroll
  for (int o = 32; o > 0; o >>= 1) ssum += __shfl_xor(ssum, o);
  out_scores[(size_t)row * E + lane] = ev / ssum;
  // top-2 butterfly with (value desc, index asc) order — matches lax.top_k
  float v1 = v;
  int i1 = lane;
  float v2 = -3.4e38f;
  int i2 = E;
#pragma unroll
  for (int o = 32; o > 0; o >>= 1) {
    float w1 = __shfl_xor(v1, o);
    int j1 = __shfl_xor(i1, o);
    float w2 = __shfl_xor(v2, o);
    int j2 = __shfl_xor(i2, o);
    bool firstBetter = (v1 > w1) || (v1 == w1 && i1 < j1);
    float t1, t2;
    int ti1, ti2;
    if (firstBetter) {
      t1 = v1; ti1 = i1;
      bool sec = (v2 > w1) || (v2 == w1 && i2 < j1);
      t2 = sec ? v2 : w1;
      ti2 = sec ? i2 : j1;
    } else {
      t1 = w1; ti1 = j1;
      bool sec = (w2 > v1) || (w2 == v1 && j2 < i1);
      t2 = sec ? w2 : v1;
      ti2 = sec ? j2 : i1;
    }
    v1 = t1; i1 = ti1; v2 = t2; i2 = ti2;
  }
  if (lane == 0) {
    float e1 = __expf(v1 - m);
    float e2 = __expf(v2 - m);
    float inv = 1.0f / (e1 + e2);
    size_t o2 = (size_t)row * 2;
    out_w[o2] = e1 * inv;
    out_w[o2 + 1] = e2 * inv;
    out_i[o2] = (float)i1;
    out_i[o2 + 1] = (float)i2;
  }
}

extern "C" void kernel_launch(void* const* d_in, const int* in_sizes, int n_in,
                              void* d_out, int out_size, void* d_ws, size_t ws_size,
                              hipStream_t stream) {
  const float* x = (const float*)d_in[0];
  const float* W = (const float*)d_in[1];
  float* out = (float*)d_out;
  float* out_scores = out;                  // [N, 64]
  float* out_w = out + (size_t)N * E;       // [N, 2]
  float* out_i = out_w + (size_t)N * 2;     // [N, 2] (indices as floats)
  _Float16* Whi = (_Float16*)d_ws;          // 512 KB
  _Float16* Wlo = Whi + (size_t)E * H;      // 512 KB
  float* part = (float*)((char*)d_ws + 2 * 1024 * 1024);  // [KS][N][E] = 16 MB

  wsplit_kernel<<<(E * H + 255) / 256, 256, 0, stream>>>(W, Whi, Wlo);
  gemm_kernel<<<(N / BM) * KS, 512, 0, stream>>>(x, Whi, Wlo, part);
  finalize_kernel<<<N / 4, 256, 0, stream>>>(part, out_scores, out_w, out_i);
}